// Round 2
// baseline (92.551 us; speedup 1.0000x reference)
//
#include <hip/hip_runtime.h>

// SATD loss: per 8x8 block of (input-label), t = H*blk*H (H = Sylvester
// Hadamard), result = mean(|t|).  FWHT, 8 lanes per block (one per row):
// row FHT in-register, column FHT via 3 shfl_xor butterfly stages.

#define N_TOTAL ((float)(16LL * 3 * 512 * 512))   // 12,582,912

__device__ __forceinline__ void fht8(float* x) {
#pragma unroll
    for (int s = 4; s >= 1; s >>= 1) {
#pragma unroll
        for (int i = 0; i < 8; ++i) {
            if ((i & s) == 0) {
                float u = x[i], w = x[i + s];
                x[i] = u + w;
                x[i + s] = u - w;
            }
        }
    }
}

__global__ __launch_bounds__(256) void satd_kernel(const float* __restrict__ a,
                                                   const float* __restrict__ b,
                                                   float* __restrict__ out) {
    int t    = blockIdx.x * 256 + threadIdx.x;
    int lane = threadIdx.x & 63;
    int w    = t >> 6;                 // global wave id, [0, 24576)
    int wx   = w & 7;                  // which group of 8 blocks along W
    int by   = (w >> 3) & 63;          // block row
    int img  = w >> 9;                 // b*c image, [0, 48)
    int sub  = lane & 7;               // block within the wave's group of 8
    int r    = lane >> 3;              // row within the 8x8 block

    size_t base = ((size_t)img * 512 + (size_t)(by * 8 + r)) * 512
                + (size_t)(wx * 8 + sub) * 8;

    const float4* pa = reinterpret_cast<const float4*>(a + base);
    const float4* pb = reinterpret_cast<const float4*>(b + base);
    float4 a0 = pa[0], a1 = pa[1];
    float4 b0 = pb[0], b1 = pb[1];
    float x[8] = {a0.x - b0.x, a0.y - b0.y, a0.z - b0.z, a0.w - b0.w,
                  a1.x - b1.x, a1.y - b1.y, a1.z - b1.z, a1.w - b1.w};

    fht8(x);                           // row transform (d @ H)

    // column transform (H @ d): butterfly over the row index held in lane[5:3]
#pragma unroll
    for (int s = 4; s >= 1; s >>= 1) {
        int mask = s << 3;
        bool up = (lane & mask) == 0;
#pragma unroll
        for (int c = 0; c < 8; ++c) {
            float p = __shfl_xor(x[c], mask);
            x[c] = up ? (x[c] + p) : (p - x[c]);
        }
    }

    float s_ = 0.0f;
#pragma unroll
    for (int c = 0; c < 8; ++c) s_ += fabsf(x[c]);

    // 64-lane wave reduction
#pragma unroll
    for (int off = 32; off >= 1; off >>= 1) s_ += __shfl_down(s_, off);

    __shared__ float ws[4];
    int wid = threadIdx.x >> 6;
    if (lane == 0) ws[wid] = s_;
    __syncthreads();
    if (threadIdx.x == 0) {
        float tot = ws[0] + ws[1] + ws[2] + ws[3];
        atomicAdd(out, tot * (1.0f / N_TOTAL));
    }
}

extern "C" void kernel_launch(void* const* d_in, const int* in_sizes, int n_in,
                              void* d_out, int out_size, void* d_ws, size_t ws_size,
                              hipStream_t stream) {
    const float* a = (const float*)d_in[0];   // input
    const float* b = (const float*)d_in[1];   // label
    float* out = (float*)d_out;

    hipMemsetAsync(out, 0, sizeof(float), stream);
    satd_kernel<<<dim3(6144), dim3(256), 0, stream>>>(a, b, out);
}

// Round 3
// 22.562 us; speedup vs baseline: 4.1020x; 4.1020x over previous
//
#include <hip/hip_runtime.h>

// SATD loss: per 8x8 block of (input-label), t = H*blk*H (H = Sylvester
// Hadamard), result = mean(|t|).  FWHT with 8 lanes per 8x8 block (one per
// row): row FHT in-register, column FHT via 3 shfl_xor butterfly stages.
// No global atomics: per-block partials -> d_ws, tiny second kernel reduces.

#define N_TOTAL ((float)(16LL * 3 * 512 * 512))   // 12,582,912
#define PHYS_WAVES 6144                            // 1536 blocks * 4 waves
#define UPW 4                                      // wave-units per phys wave
#define GRID1 1536

__device__ __forceinline__ void fht8(float* x) {
#pragma unroll
    for (int s = 4; s >= 1; s >>= 1) {
#pragma unroll
        for (int i = 0; i < 8; ++i) {
            if ((i & s) == 0) {
                float u = x[i], w = x[i + s];
                x[i] = u + w;
                x[i + s] = u - w;
            }
        }
    }
}

__global__ __launch_bounds__(256) void satd_partial(const float* __restrict__ a,
                                                    const float* __restrict__ b,
                                                    float* __restrict__ ws) {
    int lane = threadIdx.x & 63;
    int wid  = threadIdx.x >> 6;
    int pw   = blockIdx.x * 4 + wid;   // physical wave id, [0, 6144)
    int sub  = lane & 7;               // block within the unit's group of 8
    int r    = lane >> 3;              // row within the 8x8 block

    float s_ = 0.0f;
#pragma unroll
    for (int u = 0; u < UPW; ++u) {
        int w   = pw + u * PHYS_WAVES;  // virtual wave-unit, [0, 24576)
        int wx  = w & 7;                // group of 8 blocks along W
        int by  = (w >> 3) & 63;        // block row
        int img = w >> 9;               // b*c image, [0, 48)

        size_t base = ((size_t)img * 512 + (size_t)(by * 8 + r)) * 512
                    + (size_t)(wx * 8 + sub) * 8;

        const float4* pa = reinterpret_cast<const float4*>(a + base);
        const float4* pb = reinterpret_cast<const float4*>(b + base);
        float4 a0 = pa[0], a1 = pa[1];
        float4 b0 = pb[0], b1 = pb[1];
        float x[8] = {a0.x - b0.x, a0.y - b0.y, a0.z - b0.z, a0.w - b0.w,
                      a1.x - b1.x, a1.y - b1.y, a1.z - b1.z, a1.w - b1.w};

        fht8(x);                        // row transform (blk @ H)

        // column transform (H @ blk): butterfly over row index in lane[5:3]
#pragma unroll
        for (int s = 4; s >= 1; s >>= 1) {
            int mask = s << 3;
            bool up = (lane & mask) == 0;
#pragma unroll
            for (int c = 0; c < 8; ++c) {
                float p = __shfl_xor(x[c], mask);
                x[c] = up ? (x[c] + p) : (p - x[c]);
            }
        }

#pragma unroll
        for (int c = 0; c < 8; ++c) s_ += fabsf(x[c]);
    }

    // 64-lane wave reduction
#pragma unroll
    for (int off = 32; off >= 1; off >>= 1) s_ += __shfl_down(s_, off);

    __shared__ float red[4];
    if (lane == 0) red[wid] = s_;
    __syncthreads();
    if (threadIdx.x == 0)
        ws[blockIdx.x] = red[0] + red[1] + red[2] + red[3];
}

__global__ __launch_bounds__(256) void satd_final(const float* __restrict__ ws,
                                                  float* __restrict__ out) {
    int t = threadIdx.x;
    float s_ = 0.0f;
#pragma unroll
    for (int k = 0; k < GRID1 / 256; ++k) s_ += ws[t + 256 * k];

#pragma unroll
    for (int off = 32; off >= 1; off >>= 1) s_ += __shfl_down(s_, off);

    __shared__ float red[4];
    int lane = t & 63, wid = t >> 6;
    if (lane == 0) red[wid] = s_;
    __syncthreads();
    if (t == 0)
        out[0] = (red[0] + red[1] + red[2] + red[3]) * (1.0f / N_TOTAL);
}

extern "C" void kernel_launch(void* const* d_in, const int* in_sizes, int n_in,
                              void* d_out, int out_size, void* d_ws, size_t ws_size,
                              hipStream_t stream) {
    const float* a = (const float*)d_in[0];   // input
    const float* b = (const float*)d_in[1];   // label
    float* out = (float*)d_out;
    float* ws  = (float*)d_ws;                // 1536 floats of scratch

    satd_partial<<<dim3(GRID1), dim3(256), 0, stream>>>(a, b, ws);
    satd_final<<<dim3(1), dim3(256), 0, stream>>>(ws, out);
}

// Round 4
// 22.122 us; speedup vs baseline: 4.1837x; 1.0199x over previous
//
#include <hip/hip_runtime.h>

// SATD loss: per 8x8 block of (input-label), t = H*blk*H (H = Sylvester
// Hadamard), result = mean(|t|).
// Mapping: one wave per 8x512-col... stripe of 8 rows x 256 cols (32 blocks).
// Load i = one dense 1KB row (lane L -> float4 at 4L).  Lane L holds 8 rows x
// 4 cols of block L>>1  =>  column FHT fully in-register; row FHT = one
// shfl_xor(1) stage (cols c<->c+4 across the lane pair) + 2 in-register stages.
// Partials -> d_ws (no global atomics), tiny second kernel reduces.

#define N_TOTAL ((float)(16LL * 3 * 512 * 512))   // 12,582,912
#define GRID1 1536

__global__ __launch_bounds__(256) void satd_partial(const float* __restrict__ a,
                                                    const float* __restrict__ b,
                                                    float* __restrict__ ws) {
    const int lane = threadIdx.x & 63;
    const int wid  = threadIdx.x >> 6;
    const int s    = blockIdx.x * 4 + wid;      // stripe id, [0, 6144)
    const int xh   = s & 1;                     // which 256-col half
    const int y8   = (s >> 1) & 63;             // block-row
    const int img  = s >> 7;                    // b*c image, [0, 48)

    const size_t base = (size_t)img * (512 * 512)
                      + (size_t)(y8 * 8) * 512 + (size_t)(xh * 256) + (lane << 2);

    float4 av[8], bv[8];
#pragma unroll
    for (int i = 0; i < 8; ++i)
        av[i] = *reinterpret_cast<const float4*>(a + base + (size_t)(i * 512));
#pragma unroll
    for (int i = 0; i < 8; ++i)
        bv[i] = *reinterpret_cast<const float4*>(b + base + (size_t)(i * 512));

    float v[8][4];
#pragma unroll
    for (int r = 0; r < 8; ++r) {
        v[r][0] = av[r].x - bv[r].x;
        v[r][1] = av[r].y - bv[r].y;
        v[r][2] = av[r].z - bv[r].z;
        v[r][3] = av[r].w - bv[r].w;
    }

    // ---- row FHT stage 4: global cols c <-> c+4 live in lanes L / L^1 ----
    const float sx = (lane & 1) ? -1.0f : 1.0f;   // hi lane: p - x = fma(-1,x,p)
#pragma unroll
    for (int r = 0; r < 8; ++r)
#pragma unroll
        for (int c = 0; c < 4; ++c) {
            float p = __shfl_xor(v[r][c], 1);
            v[r][c] = fmaf(sx, v[r][c], p);
        }

    // ---- row FHT stages 2,1 (local cols) ----
#pragma unroll
    for (int r = 0; r < 8; ++r) {
        float u0 = v[r][0], u1 = v[r][1], u2 = v[r][2], u3 = v[r][3];
        float t0 = u0 + u2, t2 = u0 - u2, t1 = u1 + u3, t3 = u1 - u3;
        v[r][0] = t0 + t1; v[r][1] = t0 - t1;
        v[r][2] = t2 + t3; v[r][3] = t2 - t3;
    }

    // ---- column FHT (8 rows in-register) + abs-accumulate ----
    float acc = 0.0f;
#pragma unroll
    for (int c = 0; c < 4; ++c) {
        float x0 = v[0][c], x1 = v[1][c], x2 = v[2][c], x3 = v[3][c];
        float x4 = v[4][c], x5 = v[5][c], x6 = v[6][c], x7 = v[7][c];
        float y0 = x0 + x4, y4 = x0 - x4, y1 = x1 + x5, y5 = x1 - x5;
        float y2 = x2 + x6, y6 = x2 - x6, y3 = x3 + x7, y7 = x3 - x7;
        float z0 = y0 + y2, z2 = y0 - y2, z1 = y1 + y3, z3 = y1 - y3;
        float z4 = y4 + y6, z6 = y4 - y6, z5 = y5 + y7, z7 = y5 - y7;
        acc += fabsf(z0 + z1) + fabsf(z0 - z1) + fabsf(z2 + z3) + fabsf(z2 - z3)
             + fabsf(z4 + z5) + fabsf(z4 - z5) + fabsf(z6 + z7) + fabsf(z6 - z7);
    }

    // ---- 64-lane wave reduction ----
#pragma unroll
    for (int off = 32; off >= 1; off >>= 1) acc += __shfl_down(acc, off);

    __shared__ float red[4];
    if (lane == 0) red[wid] = acc;
    __syncthreads();
    if (threadIdx.x == 0)
        ws[blockIdx.x] = red[0] + red[1] + red[2] + red[3];
}

__global__ __launch_bounds__(256) void satd_final(const float* __restrict__ ws,
                                                  float* __restrict__ out) {
    int t = threadIdx.x;
    float s_ = 0.0f;
#pragma unroll
    for (int k = 0; k < GRID1 / 256; ++k) s_ += ws[t + 256 * k];

#pragma unroll
    for (int off = 32; off >= 1; off >>= 1) s_ += __shfl_down(s_, off);

    __shared__ float red[4];
    int lane = t & 63, wid = t >> 6;
    if (lane == 0) red[wid] = s_;
    __syncthreads();
    if (t == 0)
        out[0] = (red[0] + red[1] + red[2] + red[3]) * (1.0f / N_TOTAL);
}

extern "C" void kernel_launch(void* const* d_in, const int* in_sizes, int n_in,
                              void* d_out, int out_size, void* d_ws, size_t ws_size,
                              hipStream_t stream) {
    const float* a = (const float*)d_in[0];   // input
    const float* b = (const float*)d_in[1];   // label
    float* out = (float*)d_out;
    float* ws  = (float*)d_ws;                // 1536 floats of scratch

    satd_partial<<<dim3(GRID1), dim3(256), 0, stream>>>(a, b, ws);
    satd_final<<<dim3(1), dim3(256), 0, stream>>>(ws, out);
}